// Round 7
// baseline (349.308 us; speedup 1.0000x reference)
//
#include <hip/hip_runtime.h>
#include <hip/hip_bf16.h>

// Problem constants
#define B_  128
#define T_  512
#define D_  400
#define NV  1024
#define NA  128

// Main kernel = r6-proven skeleton (105 us), staging switched to f32-direct
// (no Hbf, workspace 56 MB -> 456 KB to test the harness re-poison theory).
//   block = (b, v-chunk of 128); wave owns 32 v stationary in regs (x log2e);
//   H tiles (NT=32 rows) read f32 from global (L3-resident), converted to bf16
//   in-reg, ds_write into 2 LDS buffers; prefetch-before-compute, 1 barrier/tile.
#define LDH  424   // bf16 row pitch: 848 B = 53*16 (linear, r6-proven)
#define NT   32
#define MV   128
#define LOG2E 1.4426950408889634f

typedef __bf16 bf16_t;
typedef bf16_t bf16x8 __attribute__((ext_vector_type(8)));
typedef float  floatx4 __attribute__((ext_vector_type(4)));

__device__ inline float dot4(float4 a, float4 b) {
    return a.x * b.x + a.y * b.y + a.z * b.z + a.w * b.w;
}

// ---------------------------------------------------------------------------
// prep kernel, grid = 128 + 2048 blocks:
//   blocks [0,128)    : qacts (s2 + softmax + q_acts -> q_ws), r6-form verbatim
//   blocks [128,2176) : hw only, EIGHT rows per wave (load-latency amortized),
//                       shuffle-reduce batched 8-wide.
// ---------------------------------------------------------------------------
__global__ __launch_bounds__(256) void prep_kernel(const float* __restrict__ H,
                                                   const float* __restrict__ W,
                                                   const float* __restrict__ cu,
                                                   const float* __restrict__ Ca,
                                                   float* __restrict__ hw,
                                                   float* __restrict__ q_ws) {
    __shared__ __align__(16) float4 cu4[100];
    __shared__ float s_lds[NA];
    __shared__ float p_lds[NA];
    __shared__ float red[8];
    __shared__ __align__(16) float4 part[100];

    int tid = threadIdx.x, wave = tid >> 6, lane = tid & 63;

    if (blockIdx.x >= 128) {
        // ---- hw: rows [wid*8, wid*8+8) ----
        long wid = (long)(blockIdx.x - 128) * 4 + wave;   // [0, 8192)
        long r0 = wid * 8;
        const float* base = H + r0 * D_;
        float acc[8];
#pragma unroll
        for (int j = 0; j < 8; ++j) acc[j] = 0.f;

        if (lane < 50) {
            float4 wx = ((const float4*)W)[lane * 2];
            float4 wy = ((const float4*)W)[lane * 2 + 1];
#pragma unroll
            for (int j = 0; j < 8; ++j) {
                const float4* p = (const float4*)(base + (long)j * D_ + lane * 8);
                acc[j] = dot4(p[0], wx) + dot4(p[1], wy);
            }
        }
#pragma unroll
        for (int off = 1; off < 64; off <<= 1) {
#pragma unroll
            for (int j = 0; j < 8; ++j) acc[j] += __shfl_xor(acc[j], off, 64);
        }
        if (lane == 0) {
#pragma unroll
            for (int j = 0; j < 8; ++j) hw[r0 + j] = acc[j];
        }
        return;
    }

    // ---- qacts: b = blockIdx.x ----
    int b = blockIdx.x;

    if (tid < 100) cu4[tid] = ((const float4*)(cu + (size_t)b * D_))[tid];
    __syncthreads();

    // Phase S: 32 score rows per wave
    const float4* Cb4 = (const float4*)(Ca + (size_t)b * NA * D_);
#pragma unroll 2
    for (int i = 0; i < 32; ++i) {
        int a = wave * 32 + i;
        const float4* row = Cb4 + (size_t)a * 100;
        float acc = dot4(row[lane], cu4[lane]);
        if (lane < 36) acc += dot4(row[lane + 64], cu4[lane + 64]);
#pragma unroll
        for (int off = 1; off < 64; off <<= 1) acc += __shfl_xor(acc, off, 64);
        if (lane == 0) s_lds[a] = acc;
    }
    __syncthreads();

    // Phase A: softmax over the 128 scores
    float s = (tid < NA) ? s_lds[tid] : -3.0e38f;
    float m = s;
#pragma unroll
    for (int off = 1; off < 64; off <<= 1) m = fmaxf(m, __shfl_xor(m, off, 64));
    if (lane == 0) red[wave] = m;
    __syncthreads();
    m = fmaxf(red[0], red[1]);
    float e = (tid < NA) ? __expf(s - m) : 0.f;
    float sum = e;
#pragma unroll
    for (int off = 1; off < 64; off <<= 1) sum += __shfl_xor(sum, off, 64);
    if (lane == 0) red[4 + wave] = sum;
    __syncthreads();
    float S = red[4] + red[5];
    if (tid < NA) p_lds[tid] = e / S;
    __syncthreads();

    // Phase B: q[b, 4c..4c+3]
    int c4 = tid % 100;
    int half = tid / 100;
    float4 acc0 = {0.f, 0.f, 0.f, 0.f};
    if (tid < 200) {
        float4 acc1 = {0.f, 0.f, 0.f, 0.f};
        int a0 = half * 64;
#pragma unroll 4
        for (int a = 0; a < 64; a += 2) {
            float p0 = p_lds[a0 + a], p1 = p_lds[a0 + a + 1];
            float4 x0 = Cb4[(size_t)(a0 + a) * 100 + c4];
            float4 x1 = Cb4[(size_t)(a0 + a + 1) * 100 + c4];
            acc0.x += p0 * x0.x; acc0.y += p0 * x0.y; acc0.z += p0 * x0.z; acc0.w += p0 * x0.w;
            acc1.x += p1 * x1.x; acc1.y += p1 * x1.y; acc1.z += p1 * x1.z; acc1.w += p1 * x1.w;
        }
        acc0.x += acc1.x; acc0.y += acc1.y; acc0.z += acc1.z; acc0.w += acc1.w;
        if (half == 1) part[c4] = acc0;
    }
    __syncthreads();
    if (tid < 100) {
        float4 o = part[c4];
        o.x += acc0.x; o.y += acc0.y; o.z += acc0.z; o.w += acc0.w;
        ((float4*)(q_ws + (size_t)b * D_))[c4] = o;
    }
}

// ---------------------------------------------------------------------------
// Main kernel: r6 skeleton, f32-direct staging (no Hbf), exp2-domain softmax.
// ---------------------------------------------------------------------------
__global__ __launch_bounds__(256, 2) void main_kernel(const float* __restrict__ H,
                                                      const float* __restrict__ Cv,
                                                      const float* __restrict__ hw,
                                                      const float* __restrict__ q_ws,
                                                      const float* __restrict__ bs,
                                                      const int* __restrict__ lens,
                                                      float* __restrict__ out) {
    __shared__ bf16_t h_lds[2][NT * LDH];   // 2 x 27.1 KB -> 54.3 KB, 2 blocks/CU

    int i = blockIdx.x;
    int xcd = i & 7, vc = (i >> 3) & 7, bb = i >> 6;
    int b = xcd + 8 * bb;            // all 8 v-chunks of b land on one XCD
    int vbase = vc * MV;

    int tid = threadIdx.x;
    int wave = tid >> 6, lane = tid & 63;
    int lrow = lane & 15, quad = lane >> 4;

    int len = lens[b];
    float b0 = bs[0];

    // zero the pad columns (400..423) of both buffers once
    for (int idx = tid; idx < 2 * NT * (LDH - D_); idx += 256) {
        int bu = idx / (NT * (LDH - D_));
        int rem = idx % (NT * (LDH - D_));
        int r = rem / (LDH - D_), c = rem % (LDH - D_);
        h_lds[bu][r * LDH + D_ + c] = (bf16_t)0.0f;
    }

    // A fragments: this wave's 32 Cv rows, scaled by log2e, stationary
    bf16x8 afrag[2][13];
#pragma unroll
    for (int set = 0; set < 2; ++set) {
        const float* vrow = Cv + (size_t)(vbase + wave * 32 + set * 16 + lrow) * D_;
#pragma unroll
        for (int kk = 0; kk < 13; ++kk) {
            int k0 = kk * 32 + quad * 8;
            bf16x8 f;
            if (k0 >= D_) {
#pragma unroll
                for (int j = 0; j < 8; ++j) f[j] = (bf16_t)0.0f;
            } else {
                const float4* p = (const float4*)(vrow + k0);
                float4 x = p[0], y = p[1];
                f[0] = (bf16_t)(x.x * LOG2E); f[1] = (bf16_t)(x.y * LOG2E);
                f[2] = (bf16_t)(x.z * LOG2E); f[3] = (bf16_t)(x.w * LOG2E);
                f[4] = (bf16_t)(y.x * LOG2E); f[5] = (bf16_t)(y.y * LOG2E);
                f[6] = (bf16_t)(y.z * LOG2E); f[7] = (bf16_t)(y.w * LOG2E);
            }
            afrag[set][kk] = f;
        }
    }

    float m_s[2][4], l_s[2][4], a_s[2][4];
#pragma unroll
    for (int set = 0; set < 2; ++set)
#pragma unroll
        for (int r = 0; r < 4; ++r) { m_s[set][r] = -3.0e38f; l_s[set][r] = 0.f; a_s[set][r] = 0.f; }

    int ntiles = (len + NT - 1) / NT;
    const float* Hb = H + (size_t)b * T_ * D_;
    const float* hwb = hw + (size_t)b * T_;

    // stage: f32 global -> reg -> bf16 -> ds_write (50 x 16B chunks per row)
    auto stage_f32 = [&](int buf, int tt) {
        for (int idx = tid; idx < NT * 50; idx += 256) {
            int r = idx / 50, c = idx - r * 50;
            const float4* s = (const float4*)(Hb + (size_t)(tt * NT + r) * D_ + c * 8);
            float4 x = s[0], y = s[1];
            bf16x8 f;
            f[0] = (bf16_t)x.x; f[1] = (bf16_t)x.y; f[2] = (bf16_t)x.z; f[3] = (bf16_t)x.w;
            f[4] = (bf16_t)y.x; f[5] = (bf16_t)y.y; f[6] = (bf16_t)y.z; f[7] = (bf16_t)y.w;
            *(bf16x8*)((char*)h_lds[buf] + r * 848 + c * 16) = f;
        }
    };

    // prologue: fill buffer 0
    stage_f32(0, 0);
    __syncthreads();

    for (int tt = 0; tt < ntiles; ++tt) {
        int cur = tt & 1;
        if (tt + 1 < ntiles) stage_f32(cur ^ 1, tt + 1);   // prefetch BEFORE compute

        int t0 = tt * NT;
        float hwv[2];
#pragma unroll
        for (int s = 0; s < 2; ++s) hwv[s] = hwb[t0 + s * 16 + lrow];

        floatx4 c[2][2];
        floatx4 zero4 = {0.f, 0.f, 0.f, 0.f};
#pragma unroll
        for (int set = 0; set < 2; ++set)
#pragma unroll
            for (int s = 0; s < 2; ++s) c[set][s] = zero4;

#pragma unroll
        for (int kk = 0; kk < 13; ++kk) {
            int koff = kk * 32 + quad * 8;
#pragma unroll
            for (int s = 0; s < 2; ++s) {
                bf16x8 bfr = *(const bf16x8*)(&h_lds[cur][(s * 16 + lrow) * LDH + koff]);
                c[0][s] = __builtin_amdgcn_mfma_f32_16x16x32_bf16(afrag[0][kk], bfr, c[0][s], 0, 0, 0);
                c[1][s] = __builtin_amdgcn_mfma_f32_16x16x32_bf16(afrag[1][kk], bfr, c[1][s], 0, 0, 0);
            }
        }

        if (t0 + NT > len) {
#pragma unroll
            for (int s = 0; s < 2; ++s) {
                int t = t0 + s * 16 + lrow;
                if (t >= len) {
#pragma unroll
                    for (int set = 0; set < 2; ++set) {
                        c[set][s][0] = -3.0e38f; c[set][s][1] = -3.0e38f;
                        c[set][s][2] = -3.0e38f; c[set][s][3] = -3.0e38f;
                    }
                }
            }
        }

        // online softmax in exp2 domain (scores pre-scaled by log2e)
#pragma unroll
        for (int set = 0; set < 2; ++set)
#pragma unroll
            for (int r = 0; r < 4; ++r) {
                float cm = fmaxf(c[set][0][r], c[set][1][r]);
                float mn = fmaxf(m_s[set][r], cm);
                float alpha = __builtin_amdgcn_exp2f(m_s[set][r] - mn);
                float ps = 0.f, qs = 0.f;
#pragma unroll
                for (int s = 0; s < 2; ++s) {
                    float p = __builtin_amdgcn_exp2f(c[set][s][r] - mn);
                    ps += p;
                    qs += p * hwv[s];
                }
                l_s[set][r] = l_s[set][r] * alpha + ps;
                a_s[set][r] = a_s[set][r] * alpha + qs;
                m_s[set][r] = mn;
            }

        __syncthreads();   // all waves done reading buf[cur]; prefetch written
    }

    // y_utts reduce + write
#pragma unroll
    for (int set = 0; set < 2; ++set)
#pragma unroll
        for (int r = 0; r < 4; ++r) {
            float m = m_s[set][r], l = l_s[set][r], a = a_s[set][r];
#pragma unroll
            for (int off = 1; off < 16; off <<= 1) {
                float mo = __shfl_xor(m, off, 64);
                float lo = __shfl_xor(l, off, 64);
                float ao = __shfl_xor(a, off, 64);
                float mn = fmaxf(m, mo);
                float f1 = __builtin_amdgcn_exp2f(m - mn);
                float f2 = __builtin_amdgcn_exp2f(mo - mn);
                l = l * f1 + lo * f2;
                a = a * f1 + ao * f2;
                m = mn;
            }
            if (lrow == 0) {
                int v = vbase + wave * 32 + set * 16 + quad * 4 + r;
                out[(size_t)b * NV + v] = a / l + b0;
            }
        }

    // y_acts epilogue: this block owns (b, vbase..vbase+127)
    {
        const float4* q4 = (const float4*)(q_ws + (size_t)b * D_);
        float4 qa = q4[lane];
        float4 qb = (lane < 36) ? q4[lane + 64] : make_float4(0.f, 0.f, 0.f, 0.f);
#pragma unroll 1
        for (int ii = 0; ii < 32; ii += 4) {
            int v0 = vbase + wave * 32 + ii;
            float acc[4];
#pragma unroll
            for (int r = 0; r < 4; ++r) {
                const float4* v4 = (const float4*)(Cv + (size_t)(v0 + r) * D_);
                acc[r] = dot4(v4[lane], qa);
                if (lane < 36) acc[r] += dot4(v4[lane + 64], qb);
            }
#pragma unroll
            for (int off = 1; off < 64; off <<= 1) {
#pragma unroll
                for (int r = 0; r < 4; ++r) acc[r] += __shfl_xor(acc[r], off, 64);
            }
            if (lane == 0) {
                float4 o = make_float4(acc[0], acc[1], acc[2], acc[3]);
                *(float4*)(out + (size_t)B_ * NV + (size_t)b * NV + v0) = o;
            }
        }
    }
}

// ---------------------------------------------------------------------------
extern "C" void kernel_launch(void* const* d_in, const int* in_sizes, int n_in,
                              void* d_out, int out_size, void* d_ws, size_t ws_size,
                              hipStream_t stream) {
    const float* H    = (const float*)d_in[0];   // (B,T,D)
    const float* cu   = (const float*)d_in[1];   // (B,D)
    const float* Ca   = (const float*)d_in[2];   // (B,NA,D)
    const float* Cv   = (const float*)d_in[3];   // (NV,1,D)
    const float* W    = (const float*)d_in[4];   // (1,D)
    const float* bs   = (const float*)d_in[5];   // (1,)
    const int*   lens = (const int*)d_in[6];     // (B,)
    float* out = (float*)d_out;                  // f32: y_utts (B,NV) ++ y_acts (B,NV)

    float* hw   = (float*)d_ws;                  // B*T f32 (256 KB)
    float* q_ws = hw + (size_t)B_ * T_;          // B*D f32 (200 KB) — total 456 KB

    prep_kernel<<<dim3(128 + 2048), dim3(256), 0, stream>>>(H, W, cu, Ca, hw, q_ws);
    main_kernel<<<dim3(1024), dim3(256), 0, stream>>>(H, Cv, hw, q_ws, bs, lens, out);
}

// Round 8
// 308.515 us; speedup vs baseline: 1.1322x; 1.1322x over previous
//
#include <hip/hip_runtime.h>
#include <hip/hip_bf16.h>

// Problem constants
#define B_  128
#define T_  512
#define D_  400
#define NV  1024
#define NA  128

// Main kernel: r6 skeleton with per-wave state halved to raise occupancy.
//   Wave owns 16 v (afrag[13] = 52 regs, was 104) -> ~125 regs/wave ->
//   3 waves/SIMD allowed; LDS dbuf 2*32*832 = 53,248 B -> 3 blocks/CU.
//   => 12 waves/CU (was 8, register-capped).
//   Block = (b, v-chunk of 64); grid 2048. H tiles (NT=32) via global_load_lds
//   from PRE-SWIZZLED Hbf (16B chunk c of row r at c^(r&7), c<48 — r2/r3-proven);
//   2 LDS buffers, prefetch-before-compute, 1 barrier/tile; exp2-domain softmax.
#define LDH  416
#define NT   32
#define MV   64
#define LOG2E 1.4426950408889634f

typedef __bf16 bf16_t;
typedef bf16_t bf16x8 __attribute__((ext_vector_type(8)));
typedef float  floatx4 __attribute__((ext_vector_type(4)));

__device__ inline void async_copy16(const void* g, void* l) {
    __builtin_amdgcn_global_load_lds(
        (const __attribute__((address_space(1))) unsigned int*)g,
        (__attribute__((address_space(3))) unsigned int*)l, 16, 0, 0);
}

__device__ inline float dot4(float4 a, float4 b) {
    return a.x * b.x + a.y * b.y + a.z * b.z + a.w * b.w;
}

// ---------------------------------------------------------------------------
// prep kernel, grid = 128 + 2048 blocks:
//   blocks [0,128)    : qacts (s2 + softmax + q_acts -> q_ws), r6-form verbatim
//   blocks [128,2176) : hw + swizzled Hbf, EIGHT rows per wave.
// row = wid*8 + j  =>  swizzle key = j (wid*8 ≡ 0 mod 8).
// ---------------------------------------------------------------------------
template<int PRE>
__global__ __launch_bounds__(256) void prep_kernel(const float* __restrict__ H,
                                                   const float* __restrict__ W,
                                                   const float* __restrict__ cu,
                                                   const float* __restrict__ Ca,
                                                   float* __restrict__ hw,
                                                   bf16_t* __restrict__ Hbf,
                                                   float* __restrict__ q_ws) {
    __shared__ __align__(16) float4 cu4[100];
    __shared__ float s_lds[NA];
    __shared__ float p_lds[NA];
    __shared__ float red[8];
    __shared__ __align__(16) float4 part[100];

    int tid = threadIdx.x, wave = tid >> 6, lane = tid & 63;

    if (blockIdx.x >= 128) {
        // ---- hw + Hbf: rows [wid*8, wid*8+8) ----
        long wid = (long)(blockIdx.x - 128) * 4 + wave;   // [0, 8192)
        long r0 = wid * 8;
        const float* base = H + r0 * D_;
        float acc[8];
#pragma unroll
        for (int j = 0; j < 8; ++j) acc[j] = 0.f;

        if (lane < 50) {
            float4 wx = ((const float4*)W)[lane * 2];
            float4 wy = ((const float4*)W)[lane * 2 + 1];
            bf16_t* ob = Hbf + r0 * (long)LDH;
            int pos = lane;   // data chunks: swizzle applied per row below
#pragma unroll
            for (int j = 0; j < 8; ++j) {
                const float4* p = (const float4*)(base + (long)j * D_ + lane * 8);
                float4 x = p[0], y = p[1];
                acc[j] = dot4(x, wx) + dot4(y, wy);
                if (PRE) {
                    bf16x8 f;
                    f[0] = (bf16_t)x.x; f[1] = (bf16_t)x.y;
                    f[2] = (bf16_t)x.z; f[3] = (bf16_t)x.w;
                    f[4] = (bf16_t)y.x; f[5] = (bf16_t)y.y;
                    f[6] = (bf16_t)y.z; f[7] = (bf16_t)y.w;
                    int pj = (lane < 48) ? (pos ^ j) : pos;   // key = (r0+j)&7 = j
                    *(bf16x8*)(ob + (long)j * LDH + pj * 8) = f;
                }
            }
        } else if (PRE && lane < 52) {
            // zero pad chunks 50,51 of each row (cols 400..415), raw positions
            bf16x8 z;
#pragma unroll
            for (int jj = 0; jj < 8; ++jj) z[jj] = (bf16_t)0.0f;
            bf16_t* ob = Hbf + r0 * (long)LDH + lane * 8;
#pragma unroll
            for (int j = 0; j < 8; ++j)
                *(bf16x8*)(ob + (long)j * LDH) = z;
        }

#pragma unroll
        for (int off = 1; off < 64; off <<= 1) {
#pragma unroll
            for (int j = 0; j < 8; ++j) acc[j] += __shfl_xor(acc[j], off, 64);
        }
        if (lane == 0) {
#pragma unroll
            for (int j = 0; j < 8; ++j) hw[r0 + j] = acc[j];
        }
        return;
    }

    // ---- qacts: b = blockIdx.x (r6-verbatim) ----
    int b = blockIdx.x;

    if (tid < 100) cu4[tid] = ((const float4*)(cu + (size_t)b * D_))[tid];
    __syncthreads();

    const float4* Cb4 = (const float4*)(Ca + (size_t)b * NA * D_);
#pragma unroll 2
    for (int i = 0; i < 32; ++i) {
        int a = wave * 32 + i;
        const float4* row = Cb4 + (size_t)a * 100;
        float acc = dot4(row[lane], cu4[lane]);
        if (lane < 36) acc += dot4(row[lane + 64], cu4[lane + 64]);
#pragma unroll
        for (int off = 1; off < 64; off <<= 1) acc += __shfl_xor(acc, off, 64);
        if (lane == 0) s_lds[a] = acc;
    }
    __syncthreads();

    float s = (tid < NA) ? s_lds[tid] : -3.0e38f;
    float m = s;
#pragma unroll
    for (int off = 1; off < 64; off <<= 1) m = fmaxf(m, __shfl_xor(m, off, 64));
    if (lane == 0) red[wave] = m;
    __syncthreads();
    m = fmaxf(red[0], red[1]);
    float e = (tid < NA) ? __expf(s - m) : 0.f;
    float sum = e;
#pragma unroll
    for (int off = 1; off < 64; off <<= 1) sum += __shfl_xor(sum, off, 64);
    if (lane == 0) red[4 + wave] = sum;
    __syncthreads();
    float S = red[4] + red[5];
    if (tid < NA) p_lds[tid] = e / S;
    __syncthreads();

    int c4 = tid % 100;
    int half = tid / 100;
    float4 acc0 = {0.f, 0.f, 0.f, 0.f};
    if (tid < 200) {
        float4 acc1 = {0.f, 0.f, 0.f, 0.f};
        int a0 = half * 64;
#pragma unroll 4
        for (int a = 0; a < 64; a += 2) {
            float p0 = p_lds[a0 + a], p1 = p_lds[a0 + a + 1];
            float4 x0 = Cb4[(size_t)(a0 + a) * 100 + c4];
            float4 x1 = Cb4[(size_t)(a0 + a + 1) * 100 + c4];
            acc0.x += p0 * x0.x; acc0.y += p0 * x0.y; acc0.z += p0 * x0.z; acc0.w += p0 * x0.w;
            acc1.x += p1 * x1.x; acc1.y += p1 * x1.y; acc1.z += p1 * x1.z; acc1.w += p1 * x1.w;
        }
        acc0.x += acc1.x; acc0.y += acc1.y; acc0.z += acc1.z; acc0.w += acc1.w;
        if (half == 1) part[c4] = acc0;
    }
    __syncthreads();
    if (tid < 100) {
        float4 o = part[c4];
        o.x += acc0.x; o.y += acc0.y; o.z += acc0.z; o.w += acc0.w;
        ((float4*)(q_ws + (size_t)b * D_))[c4] = o;
    }
}

// ---------------------------------------------------------------------------
// Main kernel: 16 v per wave, 64 v per block, 3 blocks/CU target.
// ---------------------------------------------------------------------------
template<int PRE>
__global__ __launch_bounds__(256, 3) void main_kernel(const float* __restrict__ H,
                                                      const bf16_t* __restrict__ Hbf,
                                                      const float* __restrict__ Cv,
                                                      const float* __restrict__ hw,
                                                      const float* __restrict__ q_ws,
                                                      const float* __restrict__ bs,
                                                      const int* __restrict__ lens,
                                                      float* __restrict__ out) {
    __shared__ bf16_t h_lds[2][NT * LDH];   // 2 x 26,624 = 53,248 B -> 3 blocks/CU

    int i = blockIdx.x;
    int xcd = i & 7, vc = (i >> 3) & 15, bb = i >> 7;
    int b = xcd + 8 * bb;            // all 16 v-chunks of b land on one XCD
    int vbase = vc * MV;

    int tid = threadIdx.x;
    int wave = tid >> 6, lane = tid & 63;
    int lrow = lane & 15, quad = lane >> 4;

    int len = lens[b];
    float b0 = bs[0];

    if (!PRE) {
        // zero pad chunks 50,51 of every row, both buffers (raw positions)
        for (int idx = tid; idx < 2 * NT * 2; idx += 256) {
            int bu = idx >> 6, rem = idx & 63;
            int r = rem >> 1, c = 50 + (rem & 1);
            bf16x8 z;
#pragma unroll
            for (int j = 0; j < 8; ++j) z[j] = (bf16_t)0.0f;
            *(bf16x8*)((char*)h_lds[bu] + r * 832 + c * 16) = z;
        }
    }

    // A fragments: this wave's 16 Cv rows, scaled by log2e, stationary (52 regs)
    bf16x8 afrag[13];
    {
        const float* vrow = Cv + (size_t)(vbase + wave * 16 + lrow) * D_;
#pragma unroll
        for (int kk = 0; kk < 13; ++kk) {
            int k0 = kk * 32 + quad * 8;
            bf16x8 f;
            if (k0 >= D_) {
#pragma unroll
                for (int j = 0; j < 8; ++j) f[j] = (bf16_t)0.0f;
            } else {
                const float4* p = (const float4*)(vrow + k0);
                float4 x = p[0], y = p[1];
                f[0] = (bf16_t)(x.x * LOG2E); f[1] = (bf16_t)(x.y * LOG2E);
                f[2] = (bf16_t)(x.z * LOG2E); f[3] = (bf16_t)(x.w * LOG2E);
                f[4] = (bf16_t)(y.x * LOG2E); f[5] = (bf16_t)(y.y * LOG2E);
                f[6] = (bf16_t)(y.z * LOG2E); f[7] = (bf16_t)(y.w * LOG2E);
            }
            afrag[kk] = f;
        }
    }

    float m_s[4], l_s[4], a_s[4];
#pragma unroll
    for (int r = 0; r < 4; ++r) { m_s[r] = -3.0e38f; l_s[r] = 0.f; a_s[r] = 0.f; }

    int ntiles = (len + NT - 1) / NT;
    const float* Hb = H + (size_t)b * T_ * D_;
    const bf16_t* Hbfb = Hbf + (size_t)b * T_ * LDH;
    const float* hwb = hw + (size_t)b * T_;

    auto stage = [&](int buf, int tt) {
        if (PRE) {
            // linear DMA copy; Hbf bytes are pre-swizzled
            const char* gt = (const char*)(Hbfb + (size_t)tt * NT * LDH);
            char* lt = (char*)h_lds[buf];
#pragma unroll 1
            for (int off = tid * 16; off < NT * LDH * 2; off += 4096)
                async_copy16(gt + off, lt + off);
        } else {
            for (int idx = tid; idx < NT * 50; idx += 256) {
                int r = idx / 50, c = idx - r * 50;
                const float4* s = (const float4*)(Hb + (size_t)(tt * NT + r) * D_ + c * 8);
                float4 x = s[0], y = s[1];
                bf16x8 f;
                f[0] = (bf16_t)x.x; f[1] = (bf16_t)x.y; f[2] = (bf16_t)x.z; f[3] = (bf16_t)x.w;
                f[4] = (bf16_t)y.x; f[5] = (bf16_t)y.y; f[6] = (bf16_t)y.z; f[7] = (bf16_t)y.w;
                int pos = (c < 48) ? (c ^ (r & 7)) : c;
                *(bf16x8*)((char*)h_lds[buf] + r * 832 + pos * 16) = f;
            }
        }
    };

    // prologue: fill buffer 0
    stage(0, 0);
    __syncthreads();

    const int swz = (lrow & 7) << 4;
    const int rowb0 = lrow * 832;
    const int rowb1 = (16 + lrow) * 832;

    for (int tt = 0; tt < ntiles; ++tt) {
        int cur = tt & 1;
        if (tt + 1 < ntiles) stage(cur ^ 1, tt + 1);   // prefetch BEFORE compute

        int t0 = tt * NT;
        float hwv[2];
#pragma unroll
        for (int s = 0; s < 2; ++s) hwv[s] = hwb[t0 + s * 16 + lrow];

        floatx4 c0 = {0.f, 0.f, 0.f, 0.f};
        floatx4 c1 = {0.f, 0.f, 0.f, 0.f};

        const char* L = (const char*)h_lds[cur];
#pragma unroll
        for (int kk = 0; kk < 13; ++kk) {
            int koffb = kk * 64 + quad * 16;
            int o = (kk < 12) ? (koffb ^ swz) : koffb;   // chunks 48-51 raw
            bf16x8 f0 = *(const bf16x8*)(L + rowb0 + o);
            c0 = __builtin_amdgcn_mfma_f32_16x16x32_bf16(afrag[kk], f0, c0, 0, 0, 0);
            bf16x8 f1 = *(const bf16x8*)(L + rowb1 + o);
            c1 = __builtin_amdgcn_mfma_f32_16x16x32_bf16(afrag[kk], f1, c1, 0, 0, 0);
        }

        if (t0 + NT > len) {
            if (t0 + lrow >= len) {
                c0[0] = -3.0e38f; c0[1] = -3.0e38f; c0[2] = -3.0e38f; c0[3] = -3.0e38f;
            }
            if (t0 + 16 + lrow >= len) {
                c1[0] = -3.0e38f; c1[1] = -3.0e38f; c1[2] = -3.0e38f; c1[3] = -3.0e38f;
            }
        }

        // online softmax in exp2 domain (scores pre-scaled by log2e)
#pragma unroll
        for (int r = 0; r < 4; ++r) {
            float cm = fmaxf(c0[r], c1[r]);
            float mn = fmaxf(m_s[r], cm);
            float alpha = __builtin_amdgcn_exp2f(m_s[r] - mn);
            float p0 = __builtin_amdgcn_exp2f(c0[r] - mn);
            float p1 = __builtin_amdgcn_exp2f(c1[r] - mn);
            l_s[r] = l_s[r] * alpha + p0 + p1;
            a_s[r] = a_s[r] * alpha + p0 * hwv[0] + p1 * hwv[1];
            m_s[r] = mn;
        }

        __syncthreads();   // all waves done reading buf[cur]; prefetch landed
    }

    // y_utts reduce + write (reduce across the 16 t-lanes of each quad group)
#pragma unroll
    for (int r = 0; r < 4; ++r) {
        float m = m_s[r], l = l_s[r], a = a_s[r];
#pragma unroll
        for (int off = 1; off < 16; off <<= 1) {
            float mo = __shfl_xor(m, off, 64);
            float lo = __shfl_xor(l, off, 64);
            float ao = __shfl_xor(a, off, 64);
            float mn = fmaxf(m, mo);
            float f1 = __builtin_amdgcn_exp2f(m - mn);
            float f2 = __builtin_amdgcn_exp2f(mo - mn);
            l = l * f1 + lo * f2;
            a = a * f1 + ao * f2;
            m = mn;
        }
        if (lrow == 0) {
            int v = vbase + wave * 16 + quad * 4 + r;
            out[(size_t)b * NV + v] = a / l + b0;
        }
    }

    // y_acts epilogue: this block owns (b, vbase..vbase+63); wave handles 16 v
    {
        const float4* q4 = (const float4*)(q_ws + (size_t)b * D_);
        float4 qa = q4[lane];
        float4 qb = (lane < 36) ? q4[lane + 64] : make_float4(0.f, 0.f, 0.f, 0.f);
#pragma unroll 1
        for (int ii = 0; ii < 16; ii += 4) {
            int v0 = vbase + wave * 16 + ii;
            float acc[4];
#pragma unroll
            for (int r = 0; r < 4; ++r) {
                const float4* v4 = (const float4*)(Cv + (size_t)(v0 + r) * D_);
                acc[r] = dot4(v4[lane], qa);
                if (lane < 36) acc[r] += dot4(v4[lane + 64], qb);
            }
#pragma unroll
            for (int off = 1; off < 64; off <<= 1) {
#pragma unroll
                for (int r = 0; r < 4; ++r) acc[r] += __shfl_xor(acc[r], off, 64);
            }
            if (lane == 0) {
                float4 o = make_float4(acc[0], acc[1], acc[2], acc[3]);
                *(float4*)(out + (size_t)B_ * NV + (size_t)b * NV + v0) = o;
            }
        }
    }
}

// ---------------------------------------------------------------------------
extern "C" void kernel_launch(void* const* d_in, const int* in_sizes, int n_in,
                              void* d_out, int out_size, void* d_ws, size_t ws_size,
                              hipStream_t stream) {
    const float* H    = (const float*)d_in[0];   // (B,T,D)
    const float* cu   = (const float*)d_in[1];   // (B,D)
    const float* Ca   = (const float*)d_in[2];   // (B,NA,D)
    const float* Cv   = (const float*)d_in[3];   // (NV,1,D)
    const float* W    = (const float*)d_in[4];   // (1,D)
    const float* bs   = (const float*)d_in[5];   // (1,)
    const int*   lens = (const int*)d_in[6];     // (B,)
    float* out = (float*)d_out;                  // f32: y_utts (B,NV) ++ y_acts (B,NV)

    float*  hw   = (float*)d_ws;                        // B*T f32 (256 KB)
    float*  q_ws = hw + (size_t)B_ * T_;                // B*D f32 (200 KB)
    bf16_t* Hbf  = (bf16_t*)(q_ws + (size_t)B_ * D_);   // B*T*416 bf16 (54.5 MB)

    size_t need = ((size_t)B_ * T_ + (size_t)B_ * D_) * sizeof(float)
                + (size_t)B_ * T_ * LDH * sizeof(bf16_t);
    bool pre = (ws_size >= need);

    dim3 pgrid(128 + 2048);
    if (pre) {
        prep_kernel<1><<<pgrid, dim3(256), 0, stream>>>(H, W, cu, Ca, hw, Hbf, q_ws);
        main_kernel<1><<<dim3(2048), dim3(256), 0, stream>>>(H, Hbf, Cv, hw, q_ws, bs, lens, out);
    } else {
        prep_kernel<0><<<pgrid, dim3(256), 0, stream>>>(H, W, cu, Ca, hw, Hbf, q_ws);
        main_kernel<0><<<dim3(2048), dim3(256), 0, stream>>>(H, Hbf, Cv, hw, q_ws, bs, lens, out);
    }
}